// Round 10
// baseline (404.055 us; speedup 1.0000x reference)
//
#include <hip/hip_runtime.h>
#include <cfloat>

#define NEG_SLOPE 0.2f
#define BN_EPS 1e-5f
#define EDGES 1310720   // 16*4096*20
#define INV_M (1.0f / 1310720.0f)

typedef short v8s __attribute__((ext_vector_type(8)));   // 8 bf16 (4 VGPRs) MFMA frag
typedef float v4f __attribute__((ext_vector_type(4)));   // 4 fp32 MFMA acc
typedef float v2f __attribute__((ext_vector_type(2)));   // VGPR pair for v_pk_* f32

// manual bf16 RNE pack / unpack
__device__ __forceinline__ unsigned short f2bf(float f) {
  unsigned b = __float_as_uint(f);
  b += 0x7fffu + ((b >> 16) & 1u);
  return (unsigned short)(b >> 16);
}
__device__ __forceinline__ float bf2f(unsigned short s) {
  return __uint_as_float(((unsigned)s) << 16);
}

// Bit-exact replica of the numpy fp32 neg-distance.
// ROUND-0 LESSON: pk asm at unroll-2 serialized -> regression. ROUND-9 retry:
// unroll-8 gives 8 independent chains; chain is 7 ops (pre-doubled candidates
// removed the 2x mul); NEGATED norms turn both subtractions into adds so
// op_sel broadcasts cover all operands. IEEE: x-s == x+(-s) bit-exactly, and
// pow2 scaling is exact, so nd bits are unchanged from the scalar form.
// ROUND-2 LESSON: 512-thr blocks (16 waves/CU) expose latency -> -7%.
// ROUND-3 LESSON: 4q state spills under the 64-VGPR cap of (1024,8).
// ROUND-5 LESSON: issue cuts vanish into stalls UNLESS stalls removed first.
// ROUND-6 LESSON: killing serial slow-path tails (trip 24%->2%) = -23us.
// ROUND-8: k1 spills packed table; k2 gathers one dwordx4/neighbor.
__device__ __forceinline__ float sqnorm_np(float c0, float c1, float c2) {
#pragma clang fp contract(off)
  return (c0 * c0 + c1 * c1) + c2 * c2;
}
// add-form neg-distance (norms stored negated): bit-identical to
// (inner2 - xxn) - xxm. Used by staging check & the rare rebuild path.
__device__ __forceinline__ float negdist2n_np(float c0, float c1, float c2,
                                              float q0, float q1, float q2,
                                              float nxxn, float nxxm) {
#pragma clang fp contract(off)
  float inner2 = (c0 * q0 + c1 * q1) + c2 * q2;   // == 2*inner exactly
  return (inner2 + nxxn) + nxxm;
}

// 32-bit cross-lane helpers (fallback selection butterfly only)
template <int PAT>
__device__ __forceinline__ float swzf(float v) {
  return __uint_as_float((unsigned)__builtin_amdgcn_ds_swizzle((int)__float_as_uint(v), PAT));
}
template <int PAT>
__device__ __forceinline__ int swzi(int v) {
  return __builtin_amdgcn_ds_swizzle(v, PAT);
}
__device__ __forceinline__ float bpermf(int addr, float v) {
  return __uint_as_float((unsigned)__builtin_amdgcn_ds_bpermute(addr, (int)__float_as_uint(v)));
}
__device__ __forceinline__ int bpermi(int addr, int v) {
  return __builtin_amdgcn_ds_bpermute(addr, v);
}
__device__ __forceinline__ int imin2(int a, int b) { return a < b ? a : b; }

// monotone float->uint order key: total order matching (fmaxf, >) on non-NaN
__device__ __forceinline__ unsigned orderkey(float f) {
  unsigned u = __float_as_uint(f);
  return ((int)u < 0) ? ~u : (u | 0x80000000u);
}
// #set bits strictly below this lane in a 64-bit mask
__device__ __forceinline__ int mbcnt64(unsigned long long m) {
  return __builtin_amdgcn_mbcnt_hi((unsigned)(m >> 32),
         __builtin_amdgcn_mbcnt_lo((unsigned)m, 0));
}
// wave-wide sum of a per-lane 0..4 count via 3 ballots
__device__ __forceinline__ int wsum4(int c) {
  return (int)__popcll(__ballot(c & 1)) + 2 * (int)__popcll(__ballot(c & 2))
       + 4 * (int)__popcll(__ballot(c & 4));
}

// Global argmax over lanes of (value desc, index asc) -> winning index
// (uniform). Used by the rare fallback path only.
__device__ __forceinline__ int pick_max(float v0, int i0, int xaddr) {
  float m = fmaxf(v0, swzf<0x041F>(v0));     // xor 1
  m = fmaxf(m, swzf<0x081F>(m));             // xor 2
  m = fmaxf(m, swzf<0x101F>(m));             // xor 4
  m = fmaxf(m, swzf<0x201F>(m));             // xor 8
  m = fmaxf(m, swzf<0x401F>(m));             // xor 16
  float vmax = fmaxf(m, bpermf(xaddr, m));   // xor 32
  unsigned long long mask = __ballot(v0 == vmax);
  if (__popcll(mask) == 1) {                 // wave-uniform branch (common case)
    int L = (int)(__ffsll(mask) - 1);
    return __builtin_amdgcn_readlane(i0, L); // winner's index, SGPR-uniform
  }
  // tie: smallest index among lanes holding vmax (exact lax.top_k semantics)
  int t = (v0 == vmax) ? i0 : 0x7fffffff;
  t = imin2(t, swzi<0x041F>(t));
  t = imin2(t, swzi<0x081F>(t));
  t = imin2(t, swzi<0x101F>(t));
  t = imin2(t, swzi<0x201F>(t));
  t = imin2(t, swzi<0x401F>(t));
  t = imin2(t, bpermi(xaddr, t));
  return t;
}

// branchless sorted-insert into descending f32 top-3 (fallback rebuild only).
__device__ __forceinline__ void ins3f(float nd, int m,
                                      float& v0, float& v1, float& v2,
                                      int& i0, int& i1, int& i2) {
  bool g0 = nd > v0, g1 = nd > v1, g2 = nd > v2;
  int ni2 = g2 ? (g1 ? i1 : m) : i2;
  int ni1 = g1 ? (g0 ? i0 : m) : i1;
  i0 = g0 ? m : i0;
  float nv1 = __builtin_amdgcn_fmed3f(nd, v0, v1);
  float nv2 = __builtin_amdgcn_fmed3f(nd, v1, v2);
  v0 = fmaxf(v0, nd);
  v1 = nv1; v2 = nv2; i1 = ni1; i2 = ni2;
}

// branchless sorted-insert into descending f32 top-4 (hot scan).
__device__ __forceinline__ void ins4f(float nd, int m,
                                      float& v0, float& v1, float& v2, float& v3,
                                      int& i0, int& i1, int& i2, int& i3) {
  bool g0 = nd > v0, g1 = nd > v1, g2 = nd > v2, g3 = nd > v3;
  int ni3 = g3 ? (g2 ? i2 : m) : i3;
  int ni2 = g2 ? (g1 ? i1 : m) : i2;
  int ni1 = g1 ? (g0 ? i0 : m) : i1;
  i0 = g0 ? m : i0;
  float nv1 = __builtin_amdgcn_fmed3f(nd, v0, v1);
  float nv2 = __builtin_amdgcn_fmed3f(nd, v1, v2);
  float nv3 = __builtin_amdgcn_fmed3f(nd, v2, v3);
  v0 = fmaxf(v0, nd);
  v1 = nv1; v2 = nv2; v3 = nv3; i1 = ni1; i2 = ni2; i3 = ni3;
}

// Fallback: exact old 20-round serial extraction (sorted order, rebuilds on
// lane exhaustion). Triggered wave-uniformly when the fast set-select can't
// prove exactness (~1.8%/query with top-4 kept).
__device__ __forceinline__ void slow_select(float v0, float v1, float v2,
                                            int i0, int i1, int i2,
                                            const float4* xs, float4 q,
                                            int xaddr, int lane, int* outp) {
  unsigned long long rem = 0ull;
  #pragma unroll 1
  for (int r = 0; r < 20; r++) {
    int win = pick_max(v0, i0, xaddr);
    if (lane == r) outp[r] = win;
    bool own = ((win & 63) == lane);
    rem |= own ? (1ull << (win >> 6)) : 0ull;
    v0 = own ? v1 : v0;  i0 = own ? i1 : i0;
    v1 = own ? v2 : v1;  i1 = own ? i2 : i1;
    v2 = own ? -FLT_MAX : v2;  i2 = own ? 0x7fffffff : i2;
    if (own & (v0 == -FLT_MAX)) {      // exhausted: rebuild from LDS
      #pragma unroll 1
      for (int j = 0; j < 64; j++) {
        int m = (j << 6) + lane;
        float4 c = xs[m];
        float nd = negdist2n_np(c.x, c.y, c.z, q.x, q.y, q.z, q.w, c.w);
        if ((rem >> j) & 1ull) nd = -FLT_MAX;
        ins3f(nd, m, v0, v1, v2, i0, i1, i2);
      }
    }
  }
}

// ---------------- K1: KNN — float4 LDS (pre-doubled, neg-norm), 2 queries, pk-f32 dist ----------------
__global__ __launch_bounds__(1024, 8) void k1_knn(const float* __restrict__ x, int* __restrict__ idxo,
                                                  float4* __restrict__ x4o) {
  __shared__ float4 xs[4096];              // 64 KB: (2x, 2y, 2z, -||x||^2)
  int b   = blockIdx.x >> 5;
  int blk = blockIdx.x & 31;
  const float* xb = x + b * 12288;
  for (int i = threadIdx.x; i < 4096; i += 1024) {
    float a0 = xb[i], a1 = xb[4096 + i], a2 = xb[8192 + i];
    xs[i] = make_float4(2.0f * a0, 2.0f * a1, 2.0f * a2, -sqnorm_np(a0, a1, a2));
  }
  __syncthreads();

  // ROUND-8: one block per batch spills the packed table for k2's gathers
  // (k2 uses xyz only; the negated .w is unread there).
  if (blk == 0) {
    float4* xg = x4o + (b << 12);
    for (int i = threadIdx.x; i < 4096; i += 1024) xg[i] = xs[i];
  }

  int wv = threadIdx.x >> 6;
  int lane = threadIdx.x & 63;
  int wave_id = blk * 16 + wv;
  int xaddr = ((lane ^ 32) << 2);

  #pragma unroll 1
  for (int p = 0; p < 4; p++) {
    int nA = wave_id * 8 + 2 * p;
    int nB = nA + 1;
    float4 rawA = xs[nA];                  // broadcast reads
    float4 rawB = xs[nB];
    float4 qA = make_float4(0.5f * rawA.x, 0.5f * rawA.y, 0.5f * rawA.z, rawA.w);
    float4 qB = make_float4(0.5f * rawB.x, 0.5f * rawB.y, 0.5f * rawB.z, rawB.w);
    v2f qx = {qA.x, qB.x};
    v2f qy = {qA.y, qB.y};
    v2f qz = {qA.z, qB.z};
    v2f qw = {qA.w, qB.w};                 // (-xxnA, -xxnB)

    float vA0 = -FLT_MAX, vA1 = -FLT_MAX, vA2 = -FLT_MAX, vA3 = -FLT_MAX;
    float vB0 = -FLT_MAX, vB1 = -FLT_MAX, vB2 = -FLT_MAX, vB3 = -FLT_MAX;
    int   iA0 = 0x7fffffff, iA1 = 0x7fffffff, iA2 = 0x7fffffff, iA3 = 0x7fffffff;
    int   iB0 = 0x7fffffff, iB1 = 0x7fffffff, iB2 = 0x7fffffff, iB3 = 0x7fffffff;
    #pragma unroll 8
    for (int j = 0; j < 64; j++) {
      int m = (j << 6) + lane;
      v4f c = ((const v4f*)xs)[m];         // one ds_read_b128 per candidate
      v2f cxy = __builtin_shufflevector(c, c, 0, 1);  // (c0, c1)
      v2f czw = __builtin_shufflevector(c, c, 2, 3);  // (c2, -xxm)
      v2f t0, t1, t2, nd;
      // lo half = query A, hi half = query B; candidate scalars broadcast
      // via op_sel. 7 pk ops replace 14 scalar; each op IEEE f32 per half.
      asm("v_pk_mul_f32 %0, %1, %2 op_sel:[0,0] op_sel_hi:[0,1]"
          : "=v"(t0) : "v"(cxy), "v"(qx));            // c0*qx
      asm("v_pk_mul_f32 %0, %1, %2 op_sel:[1,0] op_sel_hi:[1,1]"
          : "=v"(t1) : "v"(cxy), "v"(qy));            // c1*qy
      asm("v_pk_add_f32 %0, %1, %2" : "=v"(t0) : "v"(t0), "v"(t1));   // c0q0+c1q1
      asm("v_pk_mul_f32 %0, %1, %2 op_sel:[0,0] op_sel_hi:[0,1]"
          : "=v"(t2) : "v"(czw), "v"(qz));            // c2*qz
      asm("v_pk_add_f32 %0, %1, %2" : "=v"(t0) : "v"(t0), "v"(t2));   // inner2
      asm("v_pk_add_f32 %0, %1, %2" : "=v"(t0) : "v"(t0), "v"(qw));   // + (-xxn)
      asm("v_pk_add_f32 %0, %1, %2 op_sel:[0,1] op_sel_hi:[1,1]"
          : "=v"(nd) : "v"(t0), "v"(czw));            // + (-xxm)
      ins4f(nd.x, m, vA0, vA1, vA2, vA3, iA0, iA1, iA2, iA3);
      ins4f(nd.y, m, vB0, vB1, vB2, vB3, iB0, iB1, iB2, iB3);
    }

    // ---- fast set-selection: binary search the 20th-largest orderkey ----
    // hi init 0x80000000: nd <= +0 always (self-match computes exactly +0).
    unsigned kA0 = orderkey(vA0), kA1 = orderkey(vA1), kA2 = orderkey(vA2), kA3 = orderkey(vA3);
    unsigned kB0 = orderkey(vB0), kB1 = orderkey(vB1), kB2 = orderkey(vB2), kB3 = orderkey(vB3);
    unsigned loA = 0u, hiA = 0x80000000u;
    unsigned loB = 0u, hiB = 0x80000000u;
    #pragma unroll 1
    for (int it = 0; it < 32; it++) {      // invariant: count(>hi) <= 19
      unsigned midA = loA + ((hiA - loA) >> 1);
      unsigned midB = loB + ((hiB - loB) >> 1);
      int cA = (kA0 > midA) + (kA1 > midA) + (kA2 > midA) + (kA3 > midA);
      int cB = (kB0 > midB) + (kB1 > midB) + (kB2 > midB) + (kB3 > midB);
      int tA = wsum4(cA);
      int tB = wsum4(cB);
      if (tA <= 19) hiA = midA; else loA = midA + 1;
      if (tB <= 19) hiB = midB; else loB = midB + 1;
    }
    unsigned tA = hiA, tB = hiB;           // = 20th-largest key (exists in multiset)

    // exactness guards: (a) no lane may have discarded a candidate >= t*;
    // (b) equal-count must exactly fill the quota.
    int  cgA = (kA0 > tA) + (kA1 > tA) + (kA2 > tA) + (kA3 > tA);
    int  ceA = (kA0 == tA) + (kA1 == tA) + (kA2 == tA) + (kA3 == tA);
    bool badA = (__ballot(kA3 >= tA) != 0ull) || (wsum4(ceA) != 20 - wsum4(cgA));
    int  cgB = (kB0 > tB) + (kB1 > tB) + (kB2 > tB) + (kB3 > tB);
    int  ceB = (kB0 == tB) + (kB1 == tB) + (kB2 == tB) + (kB3 == tB);
    bool badB = (__ballot(kB3 >= tB) != 0ull) || (wsum4(ceB) != 20 - wsum4(cgB));

    int baseA = ((b << 12) + nA) * 20;
    int baseB = ((b << 12) + nB) * 20;

    if (!badA) {                           // unordered exact-set emit
      int c = (kA0 >= tA) + (kA1 >= tA) + (kA2 >= tA) + (kA3 >= tA);
      unsigned long long m1 = __ballot(c >= 1);
      unsigned long long m2 = __ballot(c >= 2);
      unsigned long long m3 = __ballot(c >= 3);
      unsigned long long m4 = __ballot(c >= 4);
      int n1 = (int)__popcll(m1), n2 = (int)__popcll(m2), n3 = (int)__popcll(m3);
      if (c >= 1) idxo[baseA + mbcnt64(m1)] = iA0;
      if (c >= 2) idxo[baseA + n1 + mbcnt64(m2)] = iA1;
      if (c >= 3) idxo[baseA + n1 + n2 + mbcnt64(m3)] = iA2;
      if (c >= 4) idxo[baseA + n1 + n2 + n3 + mbcnt64(m4)] = iA3;
    } else {
      slow_select(vA0, vA1, vA2, iA0, iA1, iA2, (const float4*)xs, qA, xaddr, lane, idxo + baseA);
    }
    if (!badB) {
      int c = (kB0 >= tB) + (kB1 >= tB) + (kB2 >= tB) + (kB3 >= tB);
      unsigned long long m1 = __ballot(c >= 1);
      unsigned long long m2 = __ballot(c >= 2);
      unsigned long long m3 = __ballot(c >= 3);
      unsigned long long m4 = __ballot(c >= 4);
      int n1 = (int)__popcll(m1), n2 = (int)__popcll(m2), n3 = (int)__popcll(m3);
      if (c >= 1) idxo[baseB + mbcnt64(m1)] = iB0;
      if (c >= 2) idxo[baseB + n1 + mbcnt64(m2)] = iB1;
      if (c >= 3) idxo[baseB + n1 + n2 + mbcnt64(m3)] = iB2;
      if (c >= 4) idxo[baseB + n1 + n2 + n3 + mbcnt64(m4)] = iB3;
    } else {
      slow_select(vB0, vB1, vB2, iB0, iB1, iB2, (const float4*)xs, qB, xaddr, lane, idxo + baseB);
    }
  }
}

// ---------------- K2: edge moments — packed-float4 gathers (1 load/neighbor) ----------------
__global__ __launch_bounds__(256) void k2_moments(const float4* __restrict__ x4,
                                                  const int* __restrict__ idxi,
                                                  float* __restrict__ stat) {
  int P = blockIdx.x * 256 + threadIdx.x;   // one thread per point (65536)
  int b = P >> 12, n = P & 4095;
  const float4* xb = x4 + (b << 12);
  float4 qn = xb[n];
  float xn0 = 0.5f * qn.x, xn1 = 0.5f * qn.y, xn2 = 0.5f * qn.z;
  const int* ip = idxi + P * 20;
  float Sd0 = 0.f, Sd1 = 0.f, Sd2 = 0.f;
  float S00 = 0.f, S01 = 0.f, S02 = 0.f, S11 = 0.f, S12 = 0.f, S22 = 0.f;
  #pragma unroll 4
  for (int j = 0; j < 20; j++) {
    int m = ip[j];
    float4 cm = xb[m];                      // ONE dwordx4 gather
    float d0 = 0.5f * cm.x - xn0, d1 = 0.5f * cm.y - xn1, d2 = 0.5f * cm.z - xn2;
    Sd0 += d0; Sd1 += d1; Sd2 += d2;
    S00 = fmaf(d0, d0, S00); S01 = fmaf(d0, d1, S01); S02 = fmaf(d0, d2, S02);
    S11 = fmaf(d1, d1, S11); S12 = fmaf(d1, d2, S12); S22 = fmaf(d2, d2, S22);
  }
  float acc[27];
  acc[0] = Sd0; acc[1] = Sd1; acc[2] = Sd2;
  acc[3] = 20.f * xn0; acc[4] = 20.f * xn1; acc[5] = 20.f * xn2;
  acc[6] = S00;  acc[7] = S01;  acc[8] = S02;
  acc[9] = Sd0 * xn0;  acc[10] = Sd0 * xn1; acc[11] = Sd0 * xn2;
  acc[12] = S11; acc[13] = S12;
  acc[14] = Sd1 * xn0; acc[15] = Sd1 * xn1; acc[16] = Sd1 * xn2;
  acc[17] = S22;
  acc[18] = Sd2 * xn0; acc[19] = Sd2 * xn1; acc[20] = Sd2 * xn2;
  acc[21] = 20.f * xn0 * xn0; acc[22] = 20.f * xn0 * xn1; acc[23] = 20.f * xn0 * xn2;
  acc[24] = 20.f * xn1 * xn1; acc[25] = 20.f * xn1 * xn2;
  acc[26] = 20.f * xn2 * xn2;
  #pragma unroll
  for (int i = 0; i < 27; i++) {
    float s = acc[i];
    for (int off = 32; off > 0; off >>= 1) s += __shfl_down(s, off);
    acc[i] = s;
  }
  __shared__ float red[4][27];
  int w = threadIdx.x >> 6, lane = threadIdx.x & 63;
  if (lane == 0) {
    #pragma unroll
    for (int i = 0; i < 27; i++) red[w][i] = acc[i];
  }
  __syncthreads();
  if (threadIdx.x < 27) {
    float s = red[0][threadIdx.x] + red[1][threadIdx.x] + red[2][threadIdx.x] + red[3][threadIdx.x];
    atomicAdd(&stat[threadIdx.x], s);
  }
}

// ---------------- K3c: BN1 coefficients per channel (hoisted from k0) ----------------
__global__ __launch_bounds__(64) void k3c_coef(const float* __restrict__ W0,
                                               const float* __restrict__ stat,
                                               const float* __restrict__ g0v, const float* __restrict__ b0v,
                                               float* __restrict__ ab) {
  int c = threadIdx.x;
  float w[6];
  #pragma unroll
  for (int i = 0; i < 6; i++) w[i] = W0[c * 6 + i];
  float mean = 0.f;
  #pragma unroll
  for (int i = 0; i < 6; i++) mean += w[i] * stat[i];
  mean *= INV_M;
  float e2 = 0.f;
  int pp = 6;
  #pragma unroll
  for (int i = 0; i < 6; i++) {
    #pragma unroll
    for (int j = i; j < 6; j++) {
      float f = w[i] * w[j] * stat[pp]; pp++;
      e2 += (i == j) ? f : 2.f * f;
    }
  }
  e2 *= INV_M;
  float var = e2 - mean * mean;
  float a = g0v[c] * rsqrtf(var + BN_EPS);
  ab[c] = a;
  ab[64 + c] = b0v[c] - mean * a;
}

// ---------------- K0: u,v precompute (bf16) — thread-per-point, vector stores ----------------
__global__ __launch_bounds__(256) void k0_uv(const float* __restrict__ x, const float* __restrict__ W0,
                                             const float* __restrict__ ab,
                                             unsigned short* __restrict__ u, unsigned short* __restrict__ v) {
  int P = blockIdx.x * 256 + threadIdx.x;     // one thread per point (65536)
  int b = P >> 12, n = P & 4095;
  const float* xb = x + b * 12288;
  float x0 = xb[n], x1 = xb[4096 + n], x2 = xb[8192 + n];

  #pragma unroll 1
  for (int cc = 0; cc < 64; cc += 8) {
    v8s uu8, vv8;
    #pragma unroll
    for (int k = 0; k < 8; k++) {
      int c = cc + k;
      float w0 = W0[c * 6 + 0], w1 = W0[c * 6 + 1], w2 = W0[c * 6 + 2];
      float w3 = W0[c * 6 + 3], w4 = W0[c * 6 + 4], w5 = W0[c * 6 + 5];
      float a  = ab[c];
      float bb = ab[64 + c];
      float uu = a * (w0 * x0 + w1 * x1 + w2 * x2);
      float vv = a * ((w3 - w0) * x0 + (w4 - w1) * x1 + (w5 - w2) * x2) + bb;
      uu8[k] = (short)f2bf(uu);
      vv8[k] = (short)f2bf(vv);
    }
    *(v8s*)(u + P * 64 + cc) = uu8;
    *(v8s*)(v + P * 64 + cc) = vv8;
  }
}

// ---------------- K4: conv2 via MFMA (unchanged) ----------------
__global__ __launch_bounds__(256, 4) void k4_mfma(const unsigned short* __restrict__ u,
                                                  const unsigned short* __restrict__ v,
                                                  const int* __restrict__ idxi,
                                                  const float* __restrict__ W1,
                                                  float* __restrict__ psum,
                                                  unsigned short* __restrict__ maxb,
                                                  unsigned short* __restrict__ minb) {
  int lane = threadIdx.x & 63;
  int wv = threadIdx.x >> 6;
  int g = blockIdx.x * 4 + wv;
  int G = g * 16;
  int bbase = (G >> 12) << 12;          // batch base (round-10 bug fix)
  int row16 = lane & 15;
  int quad = lane >> 4;

  v8s Bf[4][2];
  #pragma unroll
  for (int t = 0; t < 4; t++) {
    const float* wrow = W1 + (16 * t + row16) * 64 + quad * 8;
    #pragma unroll
    for (int kh = 0; kh < 2; kh++) {
      #pragma unroll
      for (int i = 0; i < 8; i++) Bf[t][kh][i] = (short)f2bf(wrow[kh * 32 + i]);
    }
  }
  const v8s* vrow = (const v8s*)(v + (G + row16) * 64);
  v8s vv0 = vrow[quad], vv1 = vrow[quad + 4];
  float v0f[8], v1f[8];
  #pragma unroll
  for (int i = 0; i < 8; i++) {
    v0f[i] = bf2f((unsigned short)vv0[i]);
    v1f[i] = bf2f((unsigned short)vv1[i]);
  }

  const int* ip = idxi + (G + row16) * 20;

  float mx[4][4], mn[4][4], s2a[4], sq2a[4];
  #pragma unroll
  for (int t = 0; t < 4; t++) {
    #pragma unroll
    for (int i = 0; i < 4; i++) { mx[t][i] = -FLT_MAX; mn[t][i] = FLT_MAX; }
    s2a[t] = 0.f; sq2a[t] = 0.f;
  }

  int m_next = ip[0];
  #pragma unroll 1
  for (int j = 0; j < 20; j++) {
    int m = bbase + m_next;
    if (j < 19) m_next = ip[j + 1];
    const v8s* urow = (const v8s*)(u + m * 64);
    v8s u0 = urow[quad], u1 = urow[quad + 4];
    v8s a0, a1f;
    #pragma unroll
    for (int i = 0; i < 8; i++) {
      float h = bf2f((unsigned short)u0[i]) + v0f[i];
      h = fmaxf(h, 0.2f * h);
      a0[i] = (short)f2bf(h);
      float h2 = bf2f((unsigned short)u1[i]) + v1f[i];
      h2 = fmaxf(h2, 0.2f * h2);
      a1f[i] = (short)f2bf(h2);
    }
    #pragma unroll
    for (int t = 0; t < 4; t++) {
      v4f c = {0.f, 0.f, 0.f, 0.f};
      c = __builtin_amdgcn_mfma_f32_16x16x32_bf16(a0, Bf[t][0], c, 0, 0, 0);
      c = __builtin_amdgcn_mfma_f32_16x16x32_bf16(a1f, Bf[t][1], c, 0, 0, 0);
      #pragma unroll
      for (int i = 0; i < 4; i++) {
        float cv = c[i];
        mx[t][i] = fmaxf(mx[t][i], cv);
        mn[t][i] = fminf(mn[t][i], cv);
        s2a[t] += cv;
        sq2a[t] = fmaf(cv, cv, sq2a[t]);
      }
    }
  }
  #pragma unroll
  for (int t = 0; t < 4; t++) {
    #pragma unroll
    for (int i = 0; i < 4; i++) {
      int P = G + quad * 4 + i;
      maxb[P * 64 + 16 * t + row16] = f2bf(mx[t][i]);
      minb[P * 64 + 16 * t + row16] = f2bf(mn[t][i]);
    }
  }
  #pragma unroll
  for (int t = 0; t < 4; t++) {
    float s = s2a[t], q = sq2a[t];
    s += __shfl_xor(s, 16); q += __shfl_xor(q, 16);
    s += __shfl_xor(s, 32); q += __shfl_xor(q, 32);
    if (quad == 0) {
      int c = 16 * t + row16;
      psum[c * 4096 + g] = s;
      psum[(64 + c) * 4096 + g] = q;
    }
  }
}

// ---------------- K4b: reduce stats2 partials ----------------
__global__ __launch_bounds__(256) void k4b_red(const float* __restrict__ psum, float* __restrict__ s2) {
  int c = blockIdx.x;
  const float* p = psum + c * 4096;
  float s = 0.f;
  for (int i = threadIdx.x; i < 4096; i += 256) s += p[i];
  for (int off = 32; off > 0; off >>= 1) s += __shfl_down(s, off);
  __shared__ float red[4];
  if ((threadIdx.x & 63) == 0) red[threadIdx.x >> 6] = s;
  __syncthreads();
  if (threadIdx.x == 0) s2[c] = red[0] + red[1] + red[2] + red[3];
}

// ---------------- K5: BN2+LReLU epilogue (unchanged) ----------------
__global__ __launch_bounds__(256) void k5_out(const unsigned short* __restrict__ maxb,
                                              const unsigned short* __restrict__ minb,
                                              const float* __restrict__ s2, const float* __restrict__ g1,
                                              const float* __restrict__ b1, float* __restrict__ out) {
  __shared__ float T[64][65];
  __shared__ float a2s[64], b2s[64];
  int blk = blockIdx.x;
  int b = blk >> 6;
  int n0 = (blk & 63) << 6;
  int t = threadIdx.x;
  if (t < 64) {
    float mean = s2[t] * INV_M;
    float var = s2[64 + t] * INV_M - mean * mean;
    float a = g1[t] * rsqrtf(var + BN_EPS);
    a2s[t] = a;
    b2s[t] = b1[t] - mean * a;
  }
  __syncthreads();
  #pragma unroll
  for (int i = 0; i < 16; i++) {
    int lin = i * 256 + t;
    int r = lin >> 6;
    int c = lin & 63;
    float a = a2s[c];
    int P = (b << 12) + n0 + r;
    float vfp = bf2f((a >= 0.f) ? maxb[P * 64 + c] : minb[P * 64 + c]);
    float z = a * vfp + b2s[c];
    T[c][r] = z >= 0.f ? z : NEG_SLOPE * z;
  }
  __syncthreads();
  #pragma unroll
  for (int i = 0; i < 16; i++) {
    int lin = i * 256 + t;
    int c = lin >> 6;
    int nn = lin & 63;
    out[(b * 64 + c) * 4096 + n0 + nn] = T[c][nn];
  }
}

extern "C" void kernel_launch(void* const* d_in, const int* in_sizes, int n_in,
                              void* d_out, int out_size, void* d_ws, size_t ws_size,
                              hipStream_t stream) {
  const float* x  = (const float*)d_in[0];
  const float* W0 = (const float*)d_in[1];
  const float* g0 = (const float*)d_in[2];
  const float* b0 = (const float*)d_in[3];
  const float* W1 = (const float*)d_in[4];
  const float* g1 = (const float*)d_in[5];
  const float* b1 = (const float*)d_in[6];
  float* out = (float*)d_out;
  char* ws = (char*)d_ws;

  // ws layout (bytes) — total ~40.9 MB. ab lives in the stat slot's spare
  // bytes; x4 (1MB) aliases the FIRST HALF of part (k1 writes, k2 reads,
  // k4 overwrites later — stream-ordered).
  int*            idx  = (int*)(ws + 0);                   // 5,242,880
  float*          stat = (float*)(ws + 5242880);           // 27 f (zeroed)
  float*          ab   = (float*)(ws + 5242880 + 512);     // 128 f (a, bb)
  float*          s2   = (float*)(ws + 5242880 + 1024);    // 128 f
  float*          part = (float*)(ws + 5244416);           // [128][4096] = 2,097,152
  float4*         x4   = (float4*)(ws + 5244416);          // 1 MB alias of part
  unsigned short* u    = (unsigned short*)(ws + 7341568);  // 8,388,608
  unsigned short* v    = (unsigned short*)(ws + 15730176); // 8,388,608
  unsigned short* maxb = (unsigned short*)(ws + 24118784); // 8,388,608
  unsigned short* minb = (unsigned short*)(ws + 32507392); // 8,388,608

  (void)hipMemsetAsync(stat, 0, 128, stream);
  k1_knn    <<<512, 1024, 0, stream>>>(x, idx, x4);
  k2_moments<<<256, 256, 0, stream>>>(x4, idx, stat);
  k3c_coef  <<<1, 64, 0, stream>>>(W0, stat, g0, b0, ab);
  k0_uv     <<<256, 256, 0, stream>>>(x, W0, ab, u, v);
  k4_mfma   <<<1024, 256, 0, stream>>>(u, v, idx, W1, part, maxb, minb);
  k4b_red   <<<128, 256, 0, stream>>>(part, s2);
  k5_out    <<<1024, 256, 0, stream>>>(maxb, minb, s2, g1, b1, out);
}

// Round 11
// 393.994 us; speedup vs baseline: 1.0255x; 1.0255x over previous
//
#include <hip/hip_runtime.h>
#include <cfloat>

#define NEG_SLOPE 0.2f
#define BN_EPS 1e-5f
#define EDGES 1310720   // 16*4096*20
#define INV_M (1.0f / 1310720.0f)

typedef short v8s __attribute__((ext_vector_type(8)));   // 8 bf16 (4 VGPRs) MFMA frag
typedef float v4f __attribute__((ext_vector_type(4)));   // 4 fp32 MFMA acc

// manual bf16 RNE pack / unpack
__device__ __forceinline__ unsigned short f2bf(float f) {
  unsigned b = __float_as_uint(f);
  b += 0x7fffu + ((b >> 16) & 1u);
  return (unsigned short)(b >> 16);
}
__device__ __forceinline__ float bf2f(unsigned short s) {
  return __uint_as_float(((unsigned)s) << 16);
}

// Bit-exact replica of the numpy fp32 neg-distance. `#pragma clang fp contract(off)`
// is the ONLY reliable way to stop -ffp-contract=fast from fusing into fmas.
// ROUND-0+9 LESSON (twice): packed v_pk_* asm for the distance chain is a
//   PERMANENT dead end — each asm statement is an opaque scheduling unit, so
//   the 7-op dependent chain can't interleave with ins4f work; +7..12us both
//   times. Scalar form is final.
// ROUND-2 LESSON: 512-thr blocks (16 waves/CU) expose latency -> -7%.
// ROUND-3 LESSON: 4q state spills under the 64-VGPR cap of (1024,8).
// ROUND-5 LESSON: k1 is stall/serialization-bound, not issue-bound.
// ROUND-6 LESSON: killing serial slow-path tails (trip 24%->2%) = -23us.
// ROUND-8: k1 (blk 0 only) spills the packed (2x,2y,2z,||x||^2) table to
// global so k2 gathers ONE dwordx4 per neighbor instead of 3 scattered
// dwords; 0.5*(2a) recovery is exact pow2 -> k2 stats bit-identical.
__device__ __forceinline__ float sqnorm_np(float c0, float c1, float c2) {
#pragma clang fp contract(off)
  return (c0 * c0 + c1 * c1) + c2 * c2;
}
__device__ __forceinline__ float negdist2_np(float c0, float c1, float c2,
                                             float q0, float q1, float q2,
                                             float xxn, float xxm) {
#pragma clang fp contract(off)
  float inner2 = (c0 * q0 + c1 * q1) + c2 * q2;   // == 2*inner exactly
  return (inner2 - xxn) - xxm;
}

// 32-bit cross-lane helpers (fallback selection butterfly only)
template <int PAT>
__device__ __forceinline__ float swzf(float v) {
  return __uint_as_float((unsigned)__builtin_amdgcn_ds_swizzle((int)__float_as_uint(v), PAT));
}
template <int PAT>
__device__ __forceinline__ int swzi(int v) {
  return __builtin_amdgcn_ds_swizzle(v, PAT);
}
__device__ __forceinline__ float bpermf(int addr, float v) {
  return __uint_as_float((unsigned)__builtin_amdgcn_ds_bpermute(addr, (int)__float_as_uint(v)));
}
__device__ __forceinline__ int bpermi(int addr, int v) {
  return __builtin_amdgcn_ds_bpermute(addr, v);
}
__device__ __forceinline__ int imin2(int a, int b) { return a < b ? a : b; }

// monotone float->uint order key: total order matching (fmaxf, >) on non-NaN
__device__ __forceinline__ unsigned orderkey(float f) {
  unsigned u = __float_as_uint(f);
  return ((int)u < 0) ? ~u : (u | 0x80000000u);
}
// #set bits strictly below this lane in a 64-bit mask
__device__ __forceinline__ int mbcnt64(unsigned long long m) {
  return __builtin_amdgcn_mbcnt_hi((unsigned)(m >> 32),
         __builtin_amdgcn_mbcnt_lo((unsigned)m, 0));
}
// wave-wide sum of a per-lane 0..4 count via 3 ballots
__device__ __forceinline__ int wsum4(int c) {
  return (int)__popcll(__ballot(c & 1)) + 2 * (int)__popcll(__ballot(c & 2))
       + 4 * (int)__popcll(__ballot(c & 4));
}

// Global argmax over lanes of (value desc, index asc) -> winning index
// (uniform). Used by the rare fallback path only.
__device__ __forceinline__ int pick_max(float v0, int i0, int xaddr) {
  float m = fmaxf(v0, swzf<0x041F>(v0));     // xor 1
  m = fmaxf(m, swzf<0x081F>(m));             // xor 2
  m = fmaxf(m, swzf<0x101F>(m));             // xor 4
  m = fmaxf(m, swzf<0x201F>(m));             // xor 8
  m = fmaxf(m, swzf<0x401F>(m));             // xor 16
  float vmax = fmaxf(m, bpermf(xaddr, m));   // xor 32
  unsigned long long mask = __ballot(v0 == vmax);
  if (__popcll(mask) == 1) {                 // wave-uniform branch (common case)
    int L = (int)(__ffsll(mask) - 1);
    return __builtin_amdgcn_readlane(i0, L); // winner's index, SGPR-uniform
  }
  // tie: smallest index among lanes holding vmax (exact lax.top_k semantics)
  int t = (v0 == vmax) ? i0 : 0x7fffffff;
  t = imin2(t, swzi<0x041F>(t));
  t = imin2(t, swzi<0x081F>(t));
  t = imin2(t, swzi<0x101F>(t));
  t = imin2(t, swzi<0x201F>(t));
  t = imin2(t, swzi<0x401F>(t));
  t = imin2(t, bpermi(xaddr, t));
  return t;
}

// branchless sorted-insert into descending f32 top-3 (fallback rebuild only).
__device__ __forceinline__ void ins3f(float nd, int m,
                                      float& v0, float& v1, float& v2,
                                      int& i0, int& i1, int& i2) {
  bool g0 = nd > v0, g1 = nd > v1, g2 = nd > v2;
  int ni2 = g2 ? (g1 ? i1 : m) : i2;
  int ni1 = g1 ? (g0 ? i0 : m) : i1;
  i0 = g0 ? m : i0;
  float nv1 = __builtin_amdgcn_fmed3f(nd, v0, v1);
  float nv2 = __builtin_amdgcn_fmed3f(nd, v1, v2);
  v0 = fmaxf(v0, nd);
  v1 = nv1; v2 = nv2; i1 = ni1; i2 = ni2;
}

// branchless sorted-insert into descending f32 top-4 (hot scan).
__device__ __forceinline__ void ins4f(float nd, int m,
                                      float& v0, float& v1, float& v2, float& v3,
                                      int& i0, int& i1, int& i2, int& i3) {
  bool g0 = nd > v0, g1 = nd > v1, g2 = nd > v2, g3 = nd > v3;
  int ni3 = g3 ? (g2 ? i2 : m) : i3;
  int ni2 = g2 ? (g1 ? i1 : m) : i2;
  int ni1 = g1 ? (g0 ? i0 : m) : i1;
  i0 = g0 ? m : i0;
  float nv1 = __builtin_amdgcn_fmed3f(nd, v0, v1);
  float nv2 = __builtin_amdgcn_fmed3f(nd, v1, v2);
  float nv3 = __builtin_amdgcn_fmed3f(nd, v2, v3);
  v0 = fmaxf(v0, nd);
  v1 = nv1; v2 = nv2; v3 = nv3; i1 = ni1; i2 = ni2; i3 = ni3;
}

// Fallback: exact old 20-round serial extraction (sorted order, rebuilds on
// lane exhaustion). Triggered wave-uniformly when the fast set-select can't
// prove exactness (~1.8%/query with top-4 kept).
__device__ __forceinline__ void slow_select(float v0, float v1, float v2,
                                            int i0, int i1, int i2,
                                            const float4* xs, float4 q,
                                            int xaddr, int lane, int* outp) {
  unsigned long long rem = 0ull;
  #pragma unroll 1
  for (int r = 0; r < 20; r++) {
    int win = pick_max(v0, i0, xaddr);
    if (lane == r) outp[r] = win;
    bool own = ((win & 63) == lane);
    rem |= own ? (1ull << (win >> 6)) : 0ull;
    v0 = own ? v1 : v0;  i0 = own ? i1 : i0;
    v1 = own ? v2 : v1;  i1 = own ? i2 : i1;
    v2 = own ? -FLT_MAX : v2;  i2 = own ? 0x7fffffff : i2;
    if (own & (v0 == -FLT_MAX)) {      // exhausted: rebuild from LDS
      #pragma unroll 1
      for (int j = 0; j < 64; j++) {
        int m = (j << 6) + lane;
        float4 c = xs[m];
        float nd = negdist2_np(c.x, c.y, c.z, q.x, q.y, q.z, q.w, c.w);
        if ((rem >> j) & 1ull) nd = -FLT_MAX;
        ins3f(nd, m, v0, v1, v2, i0, i1, i2);
      }
    }
  }
}

// ---------------- K1: KNN — float4 LDS (pre-doubled), 2 queries, top-4 + ballot-search ----------------
__global__ __launch_bounds__(1024, 8) void k1_knn(const float* __restrict__ x, int* __restrict__ idxo,
                                                  float4* __restrict__ x4o) {
  __shared__ float4 xs[4096];              // 64 KB: (2x, 2y, 2z, ||x||^2)
  int b   = blockIdx.x >> 5;
  int blk = blockIdx.x & 31;
  const float* xb = x + b * 12288;
  for (int i = threadIdx.x; i < 4096; i += 1024) {
    float a0 = xb[i], a1 = xb[4096 + i], a2 = xb[8192 + i];
    xs[i] = make_float4(2.0f * a0, 2.0f * a1, 2.0f * a2, sqnorm_np(a0, a1, a2));
  }
  __syncthreads();

  // ROUND-8: one block per batch spills the packed table for k2's gathers
  // (stream-ordered: k2 launches after k1 completes).
  if (blk == 0) {
    float4* xg = x4o + (b << 12);
    for (int i = threadIdx.x; i < 4096; i += 1024) xg[i] = xs[i];
  }

  int wv = threadIdx.x >> 6;
  int lane = threadIdx.x & 63;
  int wave_id = blk * 16 + wv;
  int xaddr = ((lane ^ 32) << 2);

  #pragma unroll 1
  for (int p = 0; p < 4; p++) {
    int nA = wave_id * 8 + 2 * p;
    int nB = nA + 1;
    float4 rawA = xs[nA];                  // broadcast reads
    float4 rawB = xs[nB];
    float4 qA = make_float4(0.5f * rawA.x, 0.5f * rawA.y, 0.5f * rawA.z, rawA.w);
    float4 qB = make_float4(0.5f * rawB.x, 0.5f * rawB.y, 0.5f * rawB.z, rawB.w);

    float vA0 = -FLT_MAX, vA1 = -FLT_MAX, vA2 = -FLT_MAX, vA3 = -FLT_MAX;
    float vB0 = -FLT_MAX, vB1 = -FLT_MAX, vB2 = -FLT_MAX, vB3 = -FLT_MAX;
    int   iA0 = 0x7fffffff, iA1 = 0x7fffffff, iA2 = 0x7fffffff, iA3 = 0x7fffffff;
    int   iB0 = 0x7fffffff, iB1 = 0x7fffffff, iB2 = 0x7fffffff, iB3 = 0x7fffffff;
    #pragma unroll 8
    for (int j = 0; j < 64; j++) {
      int m = (j << 6) + lane;
      float4 c = xs[m];                    // one ds_read_b128 per candidate
      float ndA = negdist2_np(c.x, c.y, c.z, qA.x, qA.y, qA.z, qA.w, c.w);
      ins4f(ndA, m, vA0, vA1, vA2, vA3, iA0, iA1, iA2, iA3);
      float ndB = negdist2_np(c.x, c.y, c.z, qB.x, qB.y, qB.z, qB.w, c.w);
      ins4f(ndB, m, vB0, vB1, vB2, vB3, iB0, iB1, iB2, iB3);
    }

    // ---- fast set-selection: binary search the 20th-largest orderkey ----
    // hi init 0x80000000: nd <= +0 always (self-match computes exactly +0;
    // -0 unreachable for nonzero points), so max key = key(+0) = 0x80000000.
    unsigned kA0 = orderkey(vA0), kA1 = orderkey(vA1), kA2 = orderkey(vA2), kA3 = orderkey(vA3);
    unsigned kB0 = orderkey(vB0), kB1 = orderkey(vB1), kB2 = orderkey(vB2), kB3 = orderkey(vB3);
    unsigned loA = 0u, hiA = 0x80000000u;
    unsigned loB = 0u, hiB = 0x80000000u;
    #pragma unroll 1
    for (int it = 0; it < 32; it++) {      // invariant: count(>hi) <= 19
      unsigned midA = loA + ((hiA - loA) >> 1);
      unsigned midB = loB + ((hiB - loB) >> 1);
      int cA = (kA0 > midA) + (kA1 > midA) + (kA2 > midA) + (kA3 > midA);
      int cB = (kB0 > midB) + (kB1 > midB) + (kB2 > midB) + (kB3 > midB);
      int tA = wsum4(cA);
      int tB = wsum4(cB);
      if (tA <= 19) hiA = midA; else loA = midA + 1;
      if (tB <= 19) hiB = midB; else loB = midB + 1;
    }
    unsigned tA = hiA, tB = hiB;           // = 20th-largest key (exists in multiset)

    // exactness guards: (a) no lane may have discarded a candidate >= t*
    // (lane's 4th-best >= t* -> its 5th could be in-set); (b) equal-count
    // must exactly fill the quota (bit-ties across distinct pairs).
    int  cgA = (kA0 > tA) + (kA1 > tA) + (kA2 > tA) + (kA3 > tA);
    int  ceA = (kA0 == tA) + (kA1 == tA) + (kA2 == tA) + (kA3 == tA);
    bool badA = (__ballot(kA3 >= tA) != 0ull) || (wsum4(ceA) != 20 - wsum4(cgA));
    int  cgB = (kB0 > tB) + (kB1 > tB) + (kB2 > tB) + (kB3 > tB);
    int  ceB = (kB0 == tB) + (kB1 == tB) + (kB2 == tB) + (kB3 == tB);
    bool badB = (__ballot(kB3 >= tB) != 0ull) || (wsum4(ceB) != 20 - wsum4(cgB));

    int baseA = ((b << 12) + nA) * 20;
    int baseB = ((b << 12) + nB) * 20;

    if (!badA) {                           // unordered exact-set emit (downstream
      int c = (kA0 >= tA) + (kA1 >= tA) + (kA2 >= tA) + (kA3 >= tA);
      unsigned long long m1 = __ballot(c >= 1);
      unsigned long long m2 = __ballot(c >= 2);
      unsigned long long m3 = __ballot(c >= 3);
      unsigned long long m4 = __ballot(c >= 4);
      int n1 = (int)__popcll(m1), n2 = (int)__popcll(m2), n3 = (int)__popcll(m3);
      if (c >= 1) idxo[baseA + mbcnt64(m1)] = iA0;
      if (c >= 2) idxo[baseA + n1 + mbcnt64(m2)] = iA1;
      if (c >= 3) idxo[baseA + n1 + n2 + mbcnt64(m3)] = iA2;
      if (c >= 4) idxo[baseA + n1 + n2 + n3 + mbcnt64(m4)] = iA3;
    } else {
      slow_select(vA0, vA1, vA2, iA0, iA1, iA2, xs, qA, xaddr, lane, idxo + baseA);
    }
    if (!badB) {
      int c = (kB0 >= tB) + (kB1 >= tB) + (kB2 >= tB) + (kB3 >= tB);
      unsigned long long m1 = __ballot(c >= 1);
      unsigned long long m2 = __ballot(c >= 2);
      unsigned long long m3 = __ballot(c >= 3);
      unsigned long long m4 = __ballot(c >= 4);
      int n1 = (int)__popcll(m1), n2 = (int)__popcll(m2), n3 = (int)__popcll(m3);
      if (c >= 1) idxo[baseB + mbcnt64(m1)] = iB0;
      if (c >= 2) idxo[baseB + n1 + mbcnt64(m2)] = iB1;
      if (c >= 3) idxo[baseB + n1 + n2 + mbcnt64(m3)] = iB2;
      if (c >= 4) idxo[baseB + n1 + n2 + n3 + mbcnt64(m4)] = iB3;
    } else {
      slow_select(vB0, vB1, vB2, iB0, iB1, iB2, xs, qB, xaddr, lane, idxo + baseB);
    }
  }
}

// ---------------- K2: edge moments — packed-float4 gathers (1 load/neighbor) ----------------
// ROUND-8: gathers from the packed (2x,2y,2z,.) table; 0.5*(2a) is exact, so
// every d is bit-identical to the old 3-dword-gather form.
__global__ __launch_bounds__(256) void k2_moments(const float4* __restrict__ x4,
                                                  const int* __restrict__ idxi,
                                                  float* __restrict__ stat) {
  int P = blockIdx.x * 256 + threadIdx.x;   // one thread per point (65536)
  int b = P >> 12, n = P & 4095;
  const float4* xb = x4 + (b << 12);
  float4 qn = xb[n];
  float xn0 = 0.5f * qn.x, xn1 = 0.5f * qn.y, xn2 = 0.5f * qn.z;
  const int* ip = idxi + P * 20;
  float Sd0 = 0.f, Sd1 = 0.f, Sd2 = 0.f;
  float S00 = 0.f, S01 = 0.f, S02 = 0.f, S11 = 0.f, S12 = 0.f, S22 = 0.f;
  #pragma unroll 4
  for (int j = 0; j < 20; j++) {
    int m = ip[j];
    float4 cm = xb[m];                      // ONE dwordx4 gather
    float d0 = 0.5f * cm.x - xn0, d1 = 0.5f * cm.y - xn1, d2 = 0.5f * cm.z - xn2;
    Sd0 += d0; Sd1 += d1; Sd2 += d2;
    S00 = fmaf(d0, d0, S00); S01 = fmaf(d0, d1, S01); S02 = fmaf(d0, d2, S02);
    S11 = fmaf(d1, d1, S11); S12 = fmaf(d1, d2, S12); S22 = fmaf(d2, d2, S22);
  }
  float acc[27];
  acc[0] = Sd0; acc[1] = Sd1; acc[2] = Sd2;
  acc[3] = 20.f * xn0; acc[4] = 20.f * xn1; acc[5] = 20.f * xn2;
  acc[6] = S00;  acc[7] = S01;  acc[8] = S02;
  acc[9] = Sd0 * xn0;  acc[10] = Sd0 * xn1; acc[11] = Sd0 * xn2;
  acc[12] = S11; acc[13] = S12;
  acc[14] = Sd1 * xn0; acc[15] = Sd1 * xn1; acc[16] = Sd1 * xn2;
  acc[17] = S22;
  acc[18] = Sd2 * xn0; acc[19] = Sd2 * xn1; acc[20] = Sd2 * xn2;
  acc[21] = 20.f * xn0 * xn0; acc[22] = 20.f * xn0 * xn1; acc[23] = 20.f * xn0 * xn2;
  acc[24] = 20.f * xn1 * xn1; acc[25] = 20.f * xn1 * xn2;
  acc[26] = 20.f * xn2 * xn2;
  #pragma unroll
  for (int i = 0; i < 27; i++) {
    float s = acc[i];
    for (int off = 32; off > 0; off >>= 1) s += __shfl_down(s, off);
    acc[i] = s;
  }
  __shared__ float red[4][27];
  int w = threadIdx.x >> 6, lane = threadIdx.x & 63;
  if (lane == 0) {
    #pragma unroll
    for (int i = 0; i < 27; i++) red[w][i] = acc[i];
  }
  __syncthreads();
  if (threadIdx.x < 27) {
    float s = red[0][threadIdx.x] + red[1][threadIdx.x] + red[2][threadIdx.x] + red[3][threadIdx.x];
    atomicAdd(&stat[threadIdx.x], s);
  }
}

// ---------------- K3c: BN1 coefficients per channel (hoisted from k0) ----------------
__global__ __launch_bounds__(64) void k3c_coef(const float* __restrict__ W0,
                                               const float* __restrict__ stat,
                                               const float* __restrict__ g0v, const float* __restrict__ b0v,
                                               float* __restrict__ ab) {
  int c = threadIdx.x;
  float w[6];
  #pragma unroll
  for (int i = 0; i < 6; i++) w[i] = W0[c * 6 + i];
  float mean = 0.f;
  #pragma unroll
  for (int i = 0; i < 6; i++) mean += w[i] * stat[i];
  mean *= INV_M;
  float e2 = 0.f;
  int pp = 6;
  #pragma unroll
  for (int i = 0; i < 6; i++) {
    #pragma unroll
    for (int j = i; j < 6; j++) {
      float f = w[i] * w[j] * stat[pp]; pp++;
      e2 += (i == j) ? f : 2.f * f;
    }
  }
  e2 *= INV_M;
  float var = e2 - mean * mean;
  float a = g0v[c] * rsqrtf(var + BN_EPS);
  ab[c] = a;
  ab[64 + c] = b0v[c] - mean * a;
}

// ---------------- K0: u,v precompute (bf16) — thread-per-point, vector stores ----------------
__global__ __launch_bounds__(256) void k0_uv(const float* __restrict__ x, const float* __restrict__ W0,
                                             const float* __restrict__ ab,
                                             unsigned short* __restrict__ u, unsigned short* __restrict__ v) {
  int P = blockIdx.x * 256 + threadIdx.x;     // one thread per point (65536)
  int b = P >> 12, n = P & 4095;
  const float* xb = x + b * 12288;
  float x0 = xb[n], x1 = xb[4096 + n], x2 = xb[8192 + n];

  #pragma unroll 1
  for (int cc = 0; cc < 64; cc += 8) {
    v8s uu8, vv8;
    #pragma unroll
    for (int k = 0; k < 8; k++) {
      int c = cc + k;
      float w0 = W0[c * 6 + 0], w1 = W0[c * 6 + 1], w2 = W0[c * 6 + 2];
      float w3 = W0[c * 6 + 3], w4 = W0[c * 6 + 4], w5 = W0[c * 6 + 5];
      float a  = ab[c];
      float bb = ab[64 + c];
      float uu = a * (w0 * x0 + w1 * x1 + w2 * x2);
      float vv = a * ((w3 - w0) * x0 + (w4 - w1) * x1 + (w5 - w2) * x2) + bb;
      uu8[k] = (short)f2bf(uu);
      vv8[k] = (short)f2bf(vv);
    }
    *(v8s*)(u + P * 64 + cc) = uu8;
    *(v8s*)(v + P * 64 + cc) = vv8;
  }
}

// ---------------- K4: conv2 via MFMA (unchanged) ----------------
__global__ __launch_bounds__(256, 4) void k4_mfma(const unsigned short* __restrict__ u,
                                                  const unsigned short* __restrict__ v,
                                                  const int* __restrict__ idxi,
                                                  const float* __restrict__ W1,
                                                  float* __restrict__ psum,
                                                  unsigned short* __restrict__ maxb,
                                                  unsigned short* __restrict__ minb) {
  int lane = threadIdx.x & 63;
  int wv = threadIdx.x >> 6;
  int g = blockIdx.x * 4 + wv;
  int G = g * 16;
  int bbase = (G >> 12) << 12;          // batch base (round-10 bug fix)
  int row16 = lane & 15;
  int quad = lane >> 4;

  v8s Bf[4][2];
  #pragma unroll
  for (int t = 0; t < 4; t++) {
    const float* wrow = W1 + (16 * t + row16) * 64 + quad * 8;
    #pragma unroll
    for (int kh = 0; kh < 2; kh++) {
      #pragma unroll
      for (int i = 0; i < 8; i++) Bf[t][kh][i] = (short)f2bf(wrow[kh * 32 + i]);
    }
  }
  const v8s* vrow = (const v8s*)(v + (G + row16) * 64);
  v8s vv0 = vrow[quad], vv1 = vrow[quad + 4];
  float v0f[8], v1f[8];
  #pragma unroll
  for (int i = 0; i < 8; i++) {
    v0f[i] = bf2f((unsigned short)vv0[i]);
    v1f[i] = bf2f((unsigned short)vv1[i]);
  }

  const int* ip = idxi + (G + row16) * 20;

  float mx[4][4], mn[4][4], s2a[4], sq2a[4];
  #pragma unroll
  for (int t = 0; t < 4; t++) {
    #pragma unroll
    for (int i = 0; i < 4; i++) { mx[t][i] = -FLT_MAX; mn[t][i] = FLT_MAX; }
    s2a[t] = 0.f; sq2a[t] = 0.f;
  }

  int m_next = ip[0];
  #pragma unroll 1
  for (int j = 0; j < 20; j++) {
    int m = bbase + m_next;
    if (j < 19) m_next = ip[j + 1];
    const v8s* urow = (const v8s*)(u + m * 64);
    v8s u0 = urow[quad], u1 = urow[quad + 4];
    v8s a0, a1f;
    #pragma unroll
    for (int i = 0; i < 8; i++) {
      float h = bf2f((unsigned short)u0[i]) + v0f[i];
      h = fmaxf(h, 0.2f * h);
      a0[i] = (short)f2bf(h);
      float h2 = bf2f((unsigned short)u1[i]) + v1f[i];
      h2 = fmaxf(h2, 0.2f * h2);
      a1f[i] = (short)f2bf(h2);
    }
    #pragma unroll
    for (int t = 0; t < 4; t++) {
      v4f c = {0.f, 0.f, 0.f, 0.f};
      c = __builtin_amdgcn_mfma_f32_16x16x32_bf16(a0, Bf[t][0], c, 0, 0, 0);
      c = __builtin_amdgcn_mfma_f32_16x16x32_bf16(a1f, Bf[t][1], c, 0, 0, 0);
      #pragma unroll
      for (int i = 0; i < 4; i++) {
        float cv = c[i];
        mx[t][i] = fmaxf(mx[t][i], cv);
        mn[t][i] = fminf(mn[t][i], cv);
        s2a[t] += cv;
        sq2a[t] = fmaf(cv, cv, sq2a[t]);
      }
    }
  }
  #pragma unroll
  for (int t = 0; t < 4; t++) {
    #pragma unroll
    for (int i = 0; i < 4; i++) {
      int P = G + quad * 4 + i;
      maxb[P * 64 + 16 * t + row16] = f2bf(mx[t][i]);
      minb[P * 64 + 16 * t + row16] = f2bf(mn[t][i]);
    }
  }
  #pragma unroll
  for (int t = 0; t < 4; t++) {
    float s = s2a[t], q = sq2a[t];
    s += __shfl_xor(s, 16); q += __shfl_xor(q, 16);
    s += __shfl_xor(s, 32); q += __shfl_xor(q, 32);
    if (quad == 0) {
      int c = 16 * t + row16;
      psum[c * 4096 + g] = s;
      psum[(64 + c) * 4096 + g] = q;
    }
  }
}

// ---------------- K4b: reduce stats2 partials ----------------
__global__ __launch_bounds__(256) void k4b_red(const float* __restrict__ psum, float* __restrict__ s2) {
  int c = blockIdx.x;
  const float* p = psum + c * 4096;
  float s = 0.f;
  for (int i = threadIdx.x; i < 4096; i += 256) s += p[i];
  for (int off = 32; off > 0; off >>= 1) s += __shfl_down(s, off);
  __shared__ float red[4];
  if ((threadIdx.x & 63) == 0) red[threadIdx.x >> 6] = s;
  __syncthreads();
  if (threadIdx.x == 0) s2[c] = red[0] + red[1] + red[2] + red[3];
}

// ---------------- K5: BN2+LReLU epilogue (unchanged) ----------------
__global__ __launch_bounds__(256) void k5_out(const unsigned short* __restrict__ maxb,
                                              const unsigned short* __restrict__ minb,
                                              const float* __restrict__ s2, const float* __restrict__ g1,
                                              const float* __restrict__ b1, float* __restrict__ out) {
  __shared__ float T[64][65];
  __shared__ float a2s[64], b2s[64];
  int blk = blockIdx.x;
  int b = blk >> 6;
  int n0 = (blk & 63) << 6;
  int t = threadIdx.x;
  if (t < 64) {
    float mean = s2[t] * INV_M;
    float var = s2[64 + t] * INV_M - mean * mean;
    float a = g1[t] * rsqrtf(var + BN_EPS);
    a2s[t] = a;
    b2s[t] = b1[t] - mean * a;
  }
  __syncthreads();
  #pragma unroll
  for (int i = 0; i < 16; i++) {
    int lin = i * 256 + t;
    int r = lin >> 6;
    int c = lin & 63;
    float a = a2s[c];
    int P = (b << 12) + n0 + r;
    float vfp = bf2f((a >= 0.f) ? maxb[P * 64 + c] : minb[P * 64 + c]);
    float z = a * vfp + b2s[c];
    T[c][r] = z >= 0.f ? z : NEG_SLOPE * z;
  }
  __syncthreads();
  #pragma unroll
  for (int i = 0; i < 16; i++) {
    int lin = i * 256 + t;
    int c = lin >> 6;
    int nn = lin & 63;
    out[(b * 64 + c) * 4096 + n0 + nn] = T[c][nn];
  }
}

extern "C" void kernel_launch(void* const* d_in, const int* in_sizes, int n_in,
                              void* d_out, int out_size, void* d_ws, size_t ws_size,
                              hipStream_t stream) {
  const float* x  = (const float*)d_in[0];
  const float* W0 = (const float*)d_in[1];
  const float* g0 = (const float*)d_in[2];
  const float* b0 = (const float*)d_in[3];
  const float* W1 = (const float*)d_in[4];
  const float* g1 = (const float*)d_in[5];
  const float* b1 = (const float*)d_in[6];
  float* out = (float*)d_out;
  char* ws = (char*)d_ws;

  // ws layout (bytes) — total ~40.9 MB. ab lives in the stat slot's spare
  // bytes; x4 (1MB, round-8) aliases the FIRST HALF of part: k1 writes it,
  // k2 reads it, and only later does k4 overwrite part (stream-ordered).
  int*            idx  = (int*)(ws + 0);                   // 5,242,880
  float*          stat = (float*)(ws + 5242880);           // 27 f (zeroed)
  float*          ab   = (float*)(ws + 5242880 + 512);     // 128 f (a, bb)
  float*          s2   = (float*)(ws + 5242880 + 1024);    // 128 f
  float*          part = (float*)(ws + 5244416);           // [128][4096] = 2,097,152
  float4*         x4   = (float4*)(ws + 5244416);          // 1 MB alias of part
  unsigned short* u    = (unsigned short*)(ws + 7341568);  // 8,388,608
  unsigned short* v    = (unsigned short*)(ws + 15730176); // 8,388,608
  unsigned short* maxb = (unsigned short*)(ws + 24118784); // 8,388,608
  unsigned short* minb = (unsigned short*)(ws + 32507392); // 8,388,608

  (void)hipMemsetAsync(stat, 0, 128, stream);
  k1_knn    <<<512, 1024, 0, stream>>>(x, idx, x4);
  k2_moments<<<256, 256, 0, stream>>>(x4, idx, stat);
  k3c_coef  <<<1, 64, 0, stream>>>(W0, stat, g0, b0, ab);
  k0_uv     <<<256, 256, 0, stream>>>(x, W0, ab, u, v);
  k4_mfma   <<<1024, 256, 0, stream>>>(u, v, idx, W1, part, maxb, minb);
  k4b_red   <<<128, 256, 0, stream>>>(part, s2);
  k5_out    <<<1024, 256, 0, stream>>>(maxb, minb, s2, g1, b1, out);
}